// Round 19
// baseline (261.563 us; speedup 1.0000x reference)
//
#include <hip/hip_runtime.h>
#include <hip/hip_bf16.h>
#include <cstddef>

// ---------------------------------------------------------------------------
// LSTMSeq2Seq: B=4096, L=64, T=48, H=64, NH=4, HD=16, NQ=3
// Round 19: r18's LDS-aliasing bug fixed — W2 staging removed (VT occupies
// the whole tail; there is no free LDS). attnw head-mean stays distributed
// across waves 4-7. LSTM/attn0 unchanged (r15/r14).
// ---------------------------------------------------------------------------

#define B_   4096
#define L_   64
#define T_   48
#define H_   64
#define ROWS 16      // batch rows per LSTM block
#define PADH 136     // A1 row pad (halves)
#define PADH2 72     // A2h row pad (halves)

using half8  = __attribute__((ext_vector_type(8))) _Float16;
using half4  = __attribute__((ext_vector_type(4))) _Float16;
using f32x4  = __attribute__((ext_vector_type(4))) float;

__device__ __forceinline__ float fsig(float x) {
    return __builtin_amdgcn_rcpf(1.0f + __expf(-x));
}
__device__ __forceinline__ float ftanh(float x) {
    float e = __expf(-2.0f * fabsf(x));
    float r = (1.0f - e) * __builtin_amdgcn_rcpf(1.0f + e);
    return copysignf(r, x);
}

// ---------------------------------------------------------------------------
// LSTM weight prep (one-time, all 4 layers): out[layer][gate_row 256][k 128]
// ---------------------------------------------------------------------------
__global__ void transpose_w_all_kernel(
    const float* __restrict__ W0i, const float* __restrict__ W0h,
    const float* __restrict__ W1i, const float* __restrict__ W1h,
    const float* __restrict__ W2i, const float* __restrict__ W2h,
    const float* __restrict__ W3i, const float* __restrict__ W3h,
    _Float16* __restrict__ out) {
    int idx = blockIdx.x * 256 + threadIdx.x;      // [0, 65536)
    int layer = idx >> 14, i = idx & 16383;
    const float* Wi = (layer == 0) ? W0i : (layer == 1) ? W1i : (layer == 2) ? W2i : W3i;
    const float* Wh = (layer == 0) ? W0h : (layer == 1) ? W1h : (layer == 2) ? W2h : W3h;
    int r = i >> 6, k = i & 63;
    _Float16* o = out + (size_t)layer * 32768;
    o[r * 128 + k]      = (_Float16)Wi[i];
    o[r * 128 + 64 + k] = (_Float16)Wh[i];
}

// Attention weights: wqkvh (hi plane used), woh, w1h, woT (fp32 transposed).
__global__ void split_aux_kernel(const float* __restrict__ Wqkv,
                                 const float* __restrict__ Wo,
                                 const float* __restrict__ W1,
                                 _Float16* __restrict__ wqkvh,
                                 _Float16* __restrict__ woh,
                                 _Float16* __restrict__ w1h,
                                 float* __restrict__ woT) {
    int idx = blockIdx.x * 256 + threadIdx.x;
    if (idx < 12288) {
        float v = Wqkv[idx]; _Float16 h = (_Float16)v;
        wqkvh[idx] = h; wqkvh[12288 + idx] = (_Float16)((v - (float)h) * 2048.f);
    } else if (idx < 16384) {
        int i = idx - 12288;
        float v = Wo[i]; _Float16 h = (_Float16)v;
        woh[i] = h; woh[4096 + i] = (_Float16)((v - (float)h) * 2048.f);
    } else if (idx < 18432) {
        int i = idx - 16384;
        float v = W1[i]; _Float16 h = (_Float16)v;
        w1h[i] = h; w1h[2048 + i] = (_Float16)((v - (float)h) * 2048.f);
    } else if (idx < 22528) {
        int i = idx - 18432; int r = i >> 6, k = i & 63;
        woT[k * 64 + r] = Wo[i];
    }
}

// ---------------------------------------------------------------------------
// Fused 2-layer LSTM (round-15 known-good). 256 blocks x 512 threads.
// ---------------------------------------------------------------------------
__global__ __launch_bounds__(512, 2) void lstm2_mfma_kernel(
    const float* __restrict__ inseq,
    const float* __restrict__ in0,
    const _Float16* __restrict__ w1half,
    const float* __restrict__ b1ihp, const float* __restrict__ b1hhp,
    const _Float16* __restrict__ w2half,
    const float* __restrict__ b2ihp, const float* __restrict__ b2hhp,
    const float* __restrict__ h01, const float* __restrict__ c01,
    const float* __restrict__ h02, const float* __restrict__ c02,
    _Float16* __restrict__ outh2,         // fp16 output
    float* __restrict__ hf1, float* __restrict__ cf1,
    float* __restrict__ hf2, float* __restrict__ cf2,
    int S, int mode)
{
    __shared__ __align__(16) _Float16 A1[2][16 * PADH];    // [buf][row][x|h1]
    __shared__ __align__(16) _Float16 A2h[2][16 * PADH2];  // [buf][row][h2]

    const int tid  = threadIdx.x;
    const int w    = tid >> 6;
    const int lrow = tid & 15;
    const int lkg  = (tid >> 4) & 3;
    const int row0 = blockIdx.x * ROWS;

    const bool isL2w = (w >= 4);
    const int  wl    = w & 3;
    const int  hcol  = wl * 16 + lrow;

    const _Float16* wsrc = isL2w ? w2half : w1half;
    const float* bihp = isL2w ? b2ihp : b1ihp;
    const float* bhhp = isL2w ? b2hhp : b1hhp;

    half8 whi[4][4];
    #pragma unroll
    for (int kt = 0; kt < 4; ++kt)
        #pragma unroll
        for (int g = 0; g < 4; ++g) {
            const int col = g * 64 + hcol;
            whi[kt][g] = *(const half8*)&wsrc[(size_t)col * 128 + kt * 32 + lkg * 8];
        }
    float bsv[4];
    #pragma unroll
    for (int g = 0; g < 4; ++g)
        bsv[g] = bihp[g * 64 + hcol] + bhhp[g * 64 + hcol];

    float c[4], hlast[4] = {0.f, 0.f, 0.f, 0.f};

    const float* px[4];       // L1: x(i+1) prefetch stream
    _Float16*    ph[4];       // L2: outh2 store stream

    if (!isL2w) {
        #pragma unroll
        for (int q = 0; q < 4; ++q) {
            const int r = 4 * lkg + q;
            const float* p0 = (mode == 1) ? (in0 + (size_t)(row0 + r) * 64)
                                          : (inseq + (size_t)(row0 + r) * S * 64);
            A1[0][r * PADH + hcol] = (_Float16)p0[hcol];
            float hv = h01 ? h01[(size_t)(row0 + r) * 64 + hcol] : 0.f;
            A1[0][r * PADH + 64 + hcol] = (_Float16)hv;
            c[q] = c01 ? c01[(size_t)(row0 + r) * 64 + hcol] : 0.f;
            px[q] = inseq + (size_t)(row0 + r) * S * 64 + hcol
                  + (mode == 1 ? 0 : 64);
        }
    } else {
        #pragma unroll
        for (int q = 0; q < 4; ++q) {
            const int r = 4 * lkg + q;
            float hv = h02 ? h02[(size_t)(row0 + r) * 64 + hcol] : 0.f;
            A2h[0][r * PADH2 + hcol] = (_Float16)hv;
            c[q] = c02 ? c02[(size_t)(row0 + r) * 64 + hcol] : 0.f;
            ph[q] = outh2 + (size_t)(row0 + r) * S * 64 + hcol;
        }
    }

    const int aoff = lrow * PADH + lkg * 8;

    for (int i = 0; i <= S; ++i) {
        asm volatile("s_waitcnt lgkmcnt(0)" ::: "memory");
        __builtin_amdgcn_s_barrier();
        __builtin_amdgcn_sched_barrier(0);

        if (!isL2w) {
            if (i < S) {
                float xn[4];
                if (i + 1 < S) {
                    #pragma unroll
                    for (int q = 0; q < 4; ++q) { xn[q] = *px[q]; px[q] += 64; }
                }
                const _Float16* As = A1[i & 1];
                f32x4 a0[4];
                #pragma unroll
                for (int g = 0; g < 4; ++g)
                    a0[g] = (f32x4){bsv[g], bsv[g], bsv[g], bsv[g]};
                #pragma unroll
                for (int kt = 0; kt < 4; ++kt) {
                    half8 ah = *(const half8*)&As[aoff + kt * 32];
                    #pragma unroll
                    for (int g = 0; g < 4; ++g)
                        a0[g] = __builtin_amdgcn_mfma_f32_16x16x32_f16(ah, whi[kt][g], a0[g], 0, 0, 0);
                }
                _Float16* Ad1 = A1[(i + 1) & 1];
                #pragma unroll
                for (int q = 0; q < 4; ++q) {
                    const int r = 4 * lkg + q;
                    float gi = a0[0][q], gf = a0[1][q], gg = a0[2][q], go = a0[3][q];
                    c[q] = fsig(gf) * c[q] + fsig(gi) * ftanh(gg);
                    float hv = fsig(go) * ftanh(c[q]);
                    hlast[q] = hv;
                    Ad1[r * PADH + 64 + hcol] = (_Float16)hv;
                }
                if (i + 1 < S) {
                    #pragma unroll
                    for (int q = 0; q < 4; ++q) {
                        const int r = 4 * lkg + q;
                        Ad1[r * PADH + hcol] = (_Float16)xn[q];
                    }
                }
            }
        } else {
            const int j = i - 1;
            if (j >= 0 && j < S) {
                const _Float16* Ah1 = A1[(j + 1) & 1];
                const _Float16* Ah2 = A2h[j & 1];
                f32x4 a0[4];
                #pragma unroll
                for (int g = 0; g < 4; ++g)
                    a0[g] = (f32x4){bsv[g], bsv[g], bsv[g], bsv[g]};
                #pragma unroll
                for (int kt = 0; kt < 2; ++kt) {
                    half8 ah = *(const half8*)&Ah1[lrow * PADH + 64 + kt * 32 + lkg * 8];
                    #pragma unroll
                    for (int g = 0; g < 4; ++g)
                        a0[g] = __builtin_amdgcn_mfma_f32_16x16x32_f16(ah, whi[kt][g], a0[g], 0, 0, 0);
                }
                #pragma unroll
                for (int kt = 2; kt < 4; ++kt) {
                    half8 ah = *(const half8*)&Ah2[lrow * PADH2 + (kt - 2) * 32 + lkg * 8];
                    #pragma unroll
                    for (int g = 0; g < 4; ++g)
                        a0[g] = __builtin_amdgcn_mfma_f32_16x16x32_f16(ah, whi[kt][g], a0[g], 0, 0, 0);
                }
                _Float16* Ad = A2h[(j + 1) & 1];
                #pragma unroll
                for (int q = 0; q < 4; ++q) {
                    const int r = 4 * lkg + q;
                    float gi = a0[0][q], gf = a0[1][q], gg = a0[2][q], go = a0[3][q];
                    c[q] = fsig(gf) * c[q] + fsig(gi) * ftanh(gg);
                    float hv = fsig(go) * ftanh(c[q]);
                    hlast[q] = hv;
                    _Float16 hh = (_Float16)hv;
                    Ad[r * PADH2 + hcol] = hh;
                    *ph[q] = hh; ph[q] += 64;
                }
            }
        }
    }
    if (hf1) {
        float* hdst = isL2w ? hf2 : hf1;
        float* cdst = isL2w ? cf2 : cf1;
        #pragma unroll
        for (int q = 0; q < 4; ++q) {
            const int r = 4 * lkg + q;
            hdst[(size_t)(row0 + r) * 64 + hcol] = hlast[q];
            cdst[(size_t)(row0 + r) * 64 + hcol] = c[q];
        }
    }
}

// ---------------------------------------------------------------------------
// Self-attention, last query only — v2 (round-14 known-good).
// ---------------------------------------------------------------------------
__global__ __launch_bounds__(256, 4) void attn0_v2(
    const _Float16* __restrict__ ench,
    const _Float16* __restrict__ wqkvh,
    const float* __restrict__ bqkv,
    const float* __restrict__ woT,
    const float* __restrict__ bo,
    float* __restrict__ a0last)
{
    __shared__ __align__(16) _Float16 E[64 * 72];
    __shared__ __align__(16) _Float16 K[64 * 72];
    __shared__ __align__(16) _Float16 V[64 * 72];
    __shared__ __align__(16) _Float16 Q[64 * 72];
    __shared__ float wsm[4 * 68];
    __shared__ float ov[64];
    __shared__ float part[4 * 64];

    const int b = blockIdx.x, tid = threadIdx.x;
    const int w = tid >> 6, l = tid & 63, lr = l & 15, lkg = l >> 4;

    {
        int row = tid >> 2, c0 = (tid & 3) * 16;
        const _Float16* ep = ench + (size_t)b * 4096 + row * 64 + c0;
        *(half8*)&E[row * 72 + c0]     = *(const half8*)ep;
        *(half8*)&E[row * 72 + c0 + 8] = *(const half8*)(ep + 8);
    }
    __syncthreads();

    for (int tt = w; tt < 12; tt += 4) {
        const int kind = tt >> 2;
        const int mrow = (tt & 3) * 16;
        const int wrowB = (kind == 0) ? 64 : ((kind == 1) ? 128 : 0);
        half8 ah[2];
        #pragma unroll
        for (int kt = 0; kt < 2; ++kt)
            ah[kt] = *(const half8*)&E[(mrow + lr) * 72 + kt * 32 + lkg * 8];
        _Float16* dst = (kind == 0) ? K : ((kind == 1) ? V : Q);
        #pragma unroll
        for (int nt = 0; nt < 4; ++nt) {
            const int col = nt * 16 + lr;
            const float bv = bqkv[wrowB + col];
            f32x4 a0 = (f32x4){bv, bv, bv, bv};
            #pragma unroll
            for (int kt = 0; kt < 2; ++kt) {
                half8 bh = *(const half8*)&wqkvh[(size_t)(wrowB + col) * 64 + kt * 32 + lkg * 8];
                a0 = __builtin_amdgcn_mfma_f32_16x16x32_f16(ah[kt], bh, a0, 0, 0, 0);
            }
            #pragma unroll
            for (int i = 0; i < 4; ++i)
                dst[(mrow + lkg * 4 + i) * 72 + col] = (_Float16)a0[i];
        }
    }
    __syncthreads();

    {
        const int kv = l;
        float s = 0.f;
        #pragma unroll
        for (int d = 0; d < 16; ++d)
            s += (float)Q[63 * 72 + w * 16 + d] * (float)K[kv * 72 + w * 16 + d];
        s *= 0.25f;
        float m = s;
        #pragma unroll
        for (int off = 32; off; off >>= 1) m = fmaxf(m, __shfl_xor(m, off));
        float e = __expf(s - m);
        float sum = e;
        #pragma unroll
        for (int off = 32; off; off >>= 1) sum += __shfl_xor(sum, off);
        wsm[w * 68 + kv] = e / sum;
    }
    __syncthreads();

    {
        const int d = l & 15, gr = l >> 4;
        float o = 0.f;
        #pragma unroll
        for (int k = 0; k < 16; ++k) {
            const int kv = gr * 16 + k;
            o += wsm[w * 68 + kv] * (float)V[kv * 72 + w * 16 + d];
        }
        o += __shfl_xor(o, 16);
        o += __shfl_xor(o, 32);
        if (l < 16) ov[w * 16 + l] = o;
    }
    __syncthreads();

    {
        const int j = tid & 63, g = tid >> 6;
        float p = 0.f;
        #pragma unroll
        for (int k = 0; k < 16; ++k) {
            const int kk = g * 16 + k;
            p += ov[kk] * woT[kk * 64 + j];
        }
        part[g * 64 + j] = p;
    }
    __syncthreads();
    if (tid < 64) {
        float a = bo[tid] + part[tid] + part[64 + tid] + part[128 + tid] + part[192 + tid];
        a0last[(size_t)b * 64 + tid] = a;
    }
}

// ---------------------------------------------------------------------------
// One qt's scores + softmax + strip write + PV (cross_attn helper).
// ---------------------------------------------------------------------------
__device__ __forceinline__ f32x4 score_pv_one(
    int qt, half8 qbq, const half8* ka, _Float16* strip,
    half8 vb0, half8 vb1, int lr, int lkg)
{
    f32x4 s[4];
    #pragma unroll
    for (int kvt = 0; kvt < 4; ++kvt) {
        f32x4 a0 = (f32x4){0.f, 0.f, 0.f, 0.f};
        a0 = __builtin_amdgcn_mfma_f32_16x16x32_f16(ka[kvt], qbq, a0, 0, 0, 0);
        s[kvt] = a0 * 0.25f;
    }
    float m = s[0][0];
    #pragma unroll
    for (int kvt = 0; kvt < 4; ++kvt)
        #pragma unroll
        for (int i = 0; i < 4; ++i) m = fmaxf(m, s[kvt][i]);
    m = fmaxf(m, __shfl_xor(m, 16));
    m = fmaxf(m, __shfl_xor(m, 32));
    float sum = 0.f;
    #pragma unroll
    for (int kvt = 0; kvt < 4; ++kvt)
        #pragma unroll
        for (int i = 0; i < 4; ++i) {
            float e = __expf(s[kvt][i] - m);
            s[kvt][i] = e;
            sum += e;
        }
    sum += __shfl_xor(sum, 16);
    sum += __shfl_xor(sum, 32);
    const float r = 1.0f / sum;
    #pragma unroll
    for (int kvt = 0; kvt < 4; ++kvt) {
        half4 p;
        #pragma unroll
        for (int i = 0; i < 4; ++i) p[i] = (_Float16)(s[kvt][i] * r);
        *(half4*)&strip[(qt * 16 + lr) * 72 + kvt * 16 + lkg * 4] = p;
    }
    f32x4 acc = (f32x4){0.f, 0.f, 0.f, 0.f};
    half8 wa0 = *(const half8*)&strip[(qt * 16 + lr) * 72 + 0 + lkg * 8];
    acc = __builtin_amdgcn_mfma_f32_16x16x32_f16(wa0, vb0, acc, 0, 0, 0);
    half8 wa1 = *(const half8*)&strip[(qt * 16 + lr) * 72 + 32 + lkg * 8];
    acc = __builtin_amdgcn_mfma_f32_16x16x32_f16(wa1, vb1, acc, 0, 0, 0);
    return acc;
}

// ---------------------------------------------------------------------------
// Cross-attention v7: v5 structure + attnw on waves 4-7. W2 read from global
// (r18's LDS staging removed — it aliased VT). 512 threads, 40960 B LDS.
// ---------------------------------------------------------------------------
__global__ __launch_bounds__(512, 1) void cross_attn_v7(
    const _Float16* __restrict__ ench, const _Float16* __restrict__ dech,
    const _Float16* __restrict__ wqkvh, const float* __restrict__ bqkv,
    const _Float16* __restrict__ woh,   const float* __restrict__ bo,
    const _Float16* __restrict__ w1h,   const float* __restrict__ b1,
    const float* __restrict__ W2,       const float* __restrict__ b2,
    float* __restrict__ pred, float* __restrict__ attnw)
{
    extern __shared__ __align__(16) char smem[];
    _Float16* E  = (_Float16*)(smem);            // [64][72]
    _Float16* D  = (_Float16*)(smem + 9216);     // [48][72]
    _Float16* K  = (_Float16*)(smem + 16128);    // [64][72]
    _Float16* Q  = (_Float16*)(smem + 25344);    // [48][72]
    _Float16* VT = (_Float16*)(smem + 32256);    // [64][68] (fills tail)
    _Float16* AO = (_Float16*)(smem + 32256);    // [48][72] after PV
    float*    Hl = (float*)(smem + 32256);       // [48][36] in-place

    const int b = blockIdx.x, tid = threadIdx.x;
    const int w = tid >> 6, l = tid & 63, lr = l & 15, lkg = l >> 4;
    const int h = w & 3, half = w >> 2;

    // ---- P0: stage E, D ----------------------------------------------------
    {
        const int row = tid >> 3, c0 = (tid & 7) * 8;
        *(half8*)&E[row * 72 + c0] =
            *(const half8*)(ench + (size_t)b * 4096 + row * 64 + c0);
        if (tid < 384)
            *(half8*)&D[row * 72 + c0] =
                *(const half8*)(dech + (size_t)b * 3072 + row * 64 + c0);
    }
    __syncthreads();   // b0

    // ---- P1: K/V/Q projections (11 tiles over 8 waves) ---------------------
    for (int tt = w; tt < 11; tt += 8) {
        const int kind = (tt < 4) ? 0 : ((tt < 8) ? 1 : 2);
        const int mrow = ((kind == 0) ? tt : (kind == 1) ? tt - 4 : tt - 8) * 16;
        const int wrowB = (kind == 0) ? 64 : ((kind == 1) ? 128 : 0);
        const _Float16* S = (kind == 2) ? D : E;
        half8 ah[2];
        #pragma unroll
        for (int kt = 0; kt < 2; ++kt)
            ah[kt] = *(const half8*)&S[(mrow + lr) * 72 + kt * 32 + lkg * 8];
        #pragma unroll
        for (int nt = 0; nt < 4; ++nt) {
            const int col = nt * 16 + lr;
            const float bv = bqkv[wrowB + col];
            f32x4 a0 = (f32x4){bv, bv, bv, bv};
            #pragma unroll
            for (int kt = 0; kt < 2; ++kt) {
                half8 bh = *(const half8*)&wqkvh[(size_t)(wrowB + col) * 64 + kt * 32 + lkg * 8];
                a0 = __builtin_amdgcn_mfma_f32_16x16x32_f16(ah[kt], bh, a0, 0, 0, 0);
            }
            if (kind == 1) {
                half4 p;
                #pragma unroll
                for (int i = 0; i < 4; ++i) p[i] = (_Float16)a0[i];
                *(half4*)&VT[col * 68 + mrow + lkg * 4] = p;
            } else {
                _Float16* dst = (kind == 0) ? K : Q;
                #pragma unroll
                for (int i = 0; i < 4; ++i)
                    dst[(mrow + lkg * 4 + i) * 72 + col] = (_Float16)a0[i];
            }
        }
    }
    __syncthreads();   // b1: K/Q/VT ready

    // ---- P2a: load score fragments (per-wave qt subset) --------------------
    const half8 z = {0, 0, 0, 0, 0, 0, 0, 0};
    half8 ka[4];
    #pragma unroll
    for (int kvt = 0; kvt < 4; ++kvt)
        ka[kvt] = (lkg < 2) ? *(const half8*)&K[(kvt * 16 + lr) * 72 + h * 16 + lkg * 8] : z;
    half8 qbA = z, qbB = z;
    if (lkg < 2) {
        if (!half) {
            qbA = *(const half8*)&Q[(0 + lr) * 72 + h * 16 + lkg * 8];
            qbB = *(const half8*)&Q[(16 + lr) * 72 + h * 16 + lkg * 8];
        } else {
            qbA = *(const half8*)&Q[(32 + lr) * 72 + h * 16 + lkg * 8];
        }
    }
    __syncthreads();   // b2: K/Q/E/D dead -> strips may overwrite

    // ---- P2b: scores + softmax -> strips; PV -> regs -----------------------
    _Float16* strip = (_Float16*)(smem + ((h == 0) ? 0 : (h == 1) ? 9216
                                        : (h == 2) ? 16128 : 25344));
    half8 vb0, vb1;
    {
        half4 lo4 = *(const half4*)&VT[(h * 16 + lr) * 68 + 0 + lkg * 8];
        half4 hi4 = *(const half4*)&VT[(h * 16 + lr) * 68 + 0 + lkg * 8 + 4];
        #pragma unroll
        for (int j = 0; j < 4; ++j) { vb0[j] = lo4[j]; vb0[4 + j] = hi4[j]; }
        lo4 = *(const half4*)&VT[(h * 16 + lr) * 68 + 32 + lkg * 8];
        hi4 = *(const half4*)&VT[(h * 16 + lr) * 68 + 32 + lkg * 8 + 4];
        #pragma unroll
        for (int j = 0; j < 4; ++j) { vb1[j] = lo4[j]; vb1[4 + j] = hi4[j]; }
    }
    f32x4 pvA, pvB;
    if (!half) {
        pvA = score_pv_one(0, qbA, ka, strip, vb0, vb1, lr, lkg);
        pvB = score_pv_one(1, qbB, ka, strip, vb0, vb1, lr, lkg);
    } else {
        pvA = score_pv_one(2, qbA, ka, strip, vb0, vb1, lr, lkg);
    }
    __syncthreads();   // b3: strips written, VT reads done

    // ---- P3: AO -> LDS (VT region) -----------------------------------------
    if (!half) {
        #pragma unroll
        for (int i = 0; i < 4; ++i) {
            AO[(0 + lkg * 4 + i) * 72 + h * 16 + lr]  = (_Float16)pvA[i];
            AO[(16 + lkg * 4 + i) * 72 + h * 16 + lr] = (_Float16)pvB[i];
        }
    } else {
        #pragma unroll
        for (int i = 0; i < 4; ++i)
            AO[(32 + lkg * 4 + i) * 72 + h * 16 + lr] = (_Float16)pvA[i];
    }
    __syncthreads();   // b4: AO complete; strips intact

    if (w < 3) {
        // out-proj (swapped): A = Wo rows, B = AO rows (wave's band)
        half8 bAO[2];
        #pragma unroll
        for (int kt = 0; kt < 2; ++kt)
            bAO[kt] = *(const half8*)&AO[(w * 16 + lr) * 72 + kt * 32 + lkg * 8];
        f32x4 ov[4];
        #pragma unroll
        for (int nt = 0; nt < 4; ++nt) {
            f32x4 acc = *(const f32x4*)&bo[nt * 16 + lkg * 4];
            #pragma unroll
            for (int kt = 0; kt < 2; ++kt) {
                half8 aW = *(const half8*)&woh[(size_t)(nt * 16 + lr) * 64 + kt * 32 + lkg * 8];
                acc = __builtin_amdgcn_mfma_f32_16x16x32_f16(aW, bAO[kt], acc, 0, 0, 0);
            }
            ov[nt] = acc;
        }
        #pragma unroll
        for (int nt = 0; nt < 4; ++nt) {
            half4 p;
            #pragma unroll
            for (int i = 0; i < 4; ++i) p[i] = (_Float16)ov[nt][i];
            *(half4*)&AO[(w * 16 + lr) * 72 + nt * 16 + lkg * 4] = p;
        }
        // FC1 (swapped)
        half8 bO[2];
        #pragma unroll
        for (int kt = 0; kt < 2; ++kt)
            bO[kt] = *(const half8*)&AO[(w * 16 + lr) * 72 + kt * 32 + lkg * 8];
        #pragma unroll
        for (int nt = 0; nt < 2; ++nt) {
            f32x4 acc = *(const f32x4*)&b1[nt * 16 + lkg * 4];
            #pragma unroll
            for (int kt = 0; kt < 2; ++kt) {
                half8 aW = *(const half8*)&w1h[(size_t)(nt * 16 + lr) * 64 + kt * 32 + lkg * 8];
                acc = __builtin_amdgcn_mfma_f32_16x16x32_f16(aW, bO[kt], acc, 0, 0, 0);
            }
            f32x4 rl;
            #pragma unroll
            for (int i = 0; i < 4; ++i) rl[i] = fmaxf(acc[i], 0.f);
            *(f32x4*)&Hl[(w * 16 + lr) * 36 + nt * 16 + lkg * 4] = rl;
        }
        // FC2 (W2 from global; 96 floats, L2-hot)
        if (l < 48) {
            const int qr = l / 3, n = l - 3 * qr;
            const int q = w * 16 + qr;
            float a = b2[n];
            #pragma unroll
            for (int m2 = 0; m2 < 32; ++m2) a += Hl[q * 36 + m2] * W2[n * 32 + m2];
            pred[((size_t)b * 48 + q) * 3 + n] = a;
        }
    } else if (w >= 4) {
        // attnw = head-mean of strips, split across waves 4-7 (12 rows each)
        const _Float16* s0 = (const _Float16*)(smem);
        const _Float16* s1 = (const _Float16*)(smem + 9216);
        const _Float16* s2 = (const _Float16*)(smem + 16128);
        const _Float16* s3 = (const _Float16*)(smem + 25344);
        const int base = (w - 4) * 12;
        #pragma unroll 4
        for (int it = 0; it < 12; ++it) {
            int idx = l + (base + it) * 64;
            int o = (idx >> 6) * 72 + (idx & 63);
            attnw[(size_t)b * 3072 + idx] =
                0.25f * ((float)s0[o] + (float)s1[o] + (float)s2[o] + (float)s3[o]);
        }
    }
}

// ---------------------------------------------------------------------------
extern "C" void kernel_launch(void* const* d_in, const int* in_sizes, int n_in,
                              void* d_out, int out_size, void* d_ws, size_t ws_size,
                              hipStream_t stream) {
    const float* x      = (const float*)d_in[0];
    const float* target = (const float*)d_in[1];
    const float* eWih0 = (const float*)d_in[2],  *eWhh0 = (const float*)d_in[3];
    const float* ebih0 = (const float*)d_in[4],  *ebhh0 = (const float*)d_in[5];
    const float* eWih1 = (const float*)d_in[6],  *eWhh1 = (const float*)d_in[7];
    const float* ebih1 = (const float*)d_in[8],  *ebhh1 = (const float*)d_in[9];
    const float* dWih0 = (const float*)d_in[10], *dWhh0 = (const float*)d_in[11];
    const float* dbih0 = (const float*)d_in[12], *dbhh0 = (const float*)d_in[13];
    const float* dWih1 = (const float*)d_in[14], *dWhh1 = (const float*)d_in[15];
    const float* dbih1 = (const float*)d_in[16], *dbhh1 = (const float*)d_in[17];
    const float* Wqkv = (const float*)d_in[18], *bqkv = (const float*)d_in[19];
    const float* Wo   = (const float*)d_in[20], *bo   = (const float*)d_in[21];
    const float* W1   = (const float*)d_in[22], *b1   = (const float*)d_in[23];
    const float* W2   = (const float*)d_in[24], *b2   = (const float*)d_in[25];

    float* ws = (float*)d_ws;
    float* hseq1  = ws;
    float* encout = hseq1  + (size_t)B_ * L_ * H_;   // layout keeper
    float* decout = encout + (size_t)B_ * L_ * H_;
    float* a0last = decout + (size_t)B_ * T_ * H_;
    float* hfin   = a0last + (size_t)B_ * H_;
    float* cfin   = hfin   + (size_t)2 * B_ * H_;
    float* wtg    = cfin   + (size_t)2 * B_ * H_;
    float* auxw   = wtg    + (size_t)4 * 32768;

    _Float16* wh0 = (_Float16*)(wtg);                // [4][256][128] halves
    _Float16* wh1 = wh0 + 32768;
    _Float16* wh2 = wh1 + 32768;
    _Float16* wh3 = wh2 + 32768;
    _Float16* wqkvh = (_Float16*)auxw;               // 24576 halves
    _Float16* woh   = wqkvh + 24576;                 // 8192
    _Float16* w1h   = woh + 8192;                    // 4096
    float*    woT   = auxw + 18432;                  // 4096 floats
    _Float16* encouth = (_Float16*)hseq1;
    _Float16* decouth = encouth + (size_t)B_ * L_ * H_;

    float* pred  = (float*)d_out;
    float* attnw = pred + (size_t)B_ * T_ * 3;

    transpose_w_all_kernel<<<256, 256, 0, stream>>>(
        eWih0, eWhh0, eWih1, eWhh1, dWih0, dWhh0, dWih1, dWhh1, wh0);
    split_aux_kernel<<<88, 256, 0, stream>>>(Wqkv, Wo, W1, wqkvh, woh, w1h, woT);

    // fused encoder -> fp16 encouth
    lstm2_mfma_kernel<<<B_ / ROWS, 512, 0, stream>>>(
        x, nullptr, wh0, ebih0, ebhh0, wh1, ebih1, ebhh1,
        nullptr, nullptr, nullptr, nullptr,
        encouth, hfin, cfin, hfin + (size_t)B_ * H_, cfin + (size_t)B_ * H_,
        L_, 0);
    // self-attn, last query
    attn0_v2<<<B_, 256, 0, stream>>>(encouth, wqkvh, bqkv, woT, bo, a0last);
    // fused decoder -> fp16 decouth
    lstm2_mfma_kernel<<<B_ / ROWS, 512, 0, stream>>>(
        target, a0last, wh2, dbih0, dbhh0, wh3, dbih1, dbhh1,
        hfin, cfin, hfin + (size_t)B_ * H_, cfin + (size_t)B_ * H_,
        decouth, nullptr, nullptr, nullptr, nullptr, T_, 1);
    // cross-attention + out-proj + FC (fused epilogue) -> pred, attnw
    cross_attn_v7<<<B_, 512, 40960, stream>>>(
        encouth, decouth, wqkvh, bqkv, woh, bo, w1h, b1, W2, b2, pred, attnw);
}

// Round 20
// 255.965 us; speedup vs baseline: 1.0219x; 1.0219x over previous
//
#include <hip/hip_runtime.h>
#include <hip/hip_bf16.h>
#include <cstddef>

// ---------------------------------------------------------------------------
// LSTMSeq2Seq: B=4096, L=64, T=48, H=64, NH=4, HD=16, NQ=3
// Round 20: best-known configuration restored (== round 15, 256.3 us).
// - lstm2: gate-aligned pure-fp16 MFMA, shared h1 via A1, hoisted pointers.
// - attn0_v2: fp16 input, single-MFMA K/V/Q tiles, parallel tails.
// - cross_attn_v3: 256 thr / 4 blocks/CU staged pipeline + fused epilogue.
// Session: 2930 -> 256 us. cross_attn phase-latency floor established by
// 4 structural variants (91-95 us each); LSTM at serial-recurrence floor.
// ---------------------------------------------------------------------------

#define B_   4096
#define L_   64
#define T_   48
#define H_   64
#define ROWS 16      // batch rows per LSTM block
#define PADH 136     // A1 row pad (halves)
#define PADH2 72     // A2h row pad (halves)

using half8  = __attribute__((ext_vector_type(8))) _Float16;
using half4  = __attribute__((ext_vector_type(4))) _Float16;
using f32x4  = __attribute__((ext_vector_type(4))) float;

__device__ __forceinline__ float fsig(float x) {
    return __builtin_amdgcn_rcpf(1.0f + __expf(-x));
}
__device__ __forceinline__ float ftanh(float x) {
    float e = __expf(-2.0f * fabsf(x));
    float r = (1.0f - e) * __builtin_amdgcn_rcpf(1.0f + e);
    return copysignf(r, x);
}

// ---------------------------------------------------------------------------
// LSTM weight prep (one-time, all 4 layers): out[layer][gate_row 256][k 128]
// ---------------------------------------------------------------------------
__global__ void transpose_w_all_kernel(
    const float* __restrict__ W0i, const float* __restrict__ W0h,
    const float* __restrict__ W1i, const float* __restrict__ W1h,
    const float* __restrict__ W2i, const float* __restrict__ W2h,
    const float* __restrict__ W3i, const float* __restrict__ W3h,
    _Float16* __restrict__ out) {
    int idx = blockIdx.x * 256 + threadIdx.x;      // [0, 65536)
    int layer = idx >> 14, i = idx & 16383;
    const float* Wi = (layer == 0) ? W0i : (layer == 1) ? W1i : (layer == 2) ? W2i : W3i;
    const float* Wh = (layer == 0) ? W0h : (layer == 1) ? W1h : (layer == 2) ? W2h : W3h;
    int r = i >> 6, k = i & 63;
    _Float16* o = out + (size_t)layer * 32768;
    o[r * 128 + k]      = (_Float16)Wi[i];
    o[r * 128 + 64 + k] = (_Float16)Wh[i];
}

// Attention weights: wqkvh[2][192][64], woh[2][64][64], w1h[2][32][64],
// plus woT fp32 [k 64][j 64] for attn0's coalesced out-proj.
__global__ void split_aux_kernel(const float* __restrict__ Wqkv,
                                 const float* __restrict__ Wo,
                                 const float* __restrict__ W1,
                                 _Float16* __restrict__ wqkvh,
                                 _Float16* __restrict__ woh,
                                 _Float16* __restrict__ w1h,
                                 float* __restrict__ woT) {
    int idx = blockIdx.x * 256 + threadIdx.x;
    if (idx < 12288) {
        float v = Wqkv[idx]; _Float16 h = (_Float16)v;
        wqkvh[idx] = h; wqkvh[12288 + idx] = (_Float16)((v - (float)h) * 2048.f);
    } else if (idx < 16384) {
        int i = idx - 12288;
        float v = Wo[i]; _Float16 h = (_Float16)v;
        woh[i] = h; woh[4096 + i] = (_Float16)((v - (float)h) * 2048.f);
    } else if (idx < 18432) {
        int i = idx - 16384;
        float v = W1[i]; _Float16 h = (_Float16)v;
        w1h[i] = h; w1h[2048 + i] = (_Float16)((v - (float)h) * 2048.f);
    } else if (idx < 22528) {
        int i = idx - 18432; int r = i >> 6, k = i & 63;
        woT[k * 64 + r] = Wo[i];
    }
}

// ---------------------------------------------------------------------------
// Fused 2-layer LSTM, gate-aligned, pure-fp16 GEMM. 256 blocks x 512 thr.
// Waves 0-3: layer 1; 4-7: layer 2 (skewed one step).
// h1 shared via A1's h-part: L2 GEMM(j) reads kt 0,1 from A1[(j+1)&1].h
// (race-free: L1 cell(i=j+1) writes A1[j&1]) and kt 2,3 from A2h[j&1].
// Global pointers hoisted to per-step increments. One lgkm barrier/step.
// NEVER force min-waves=4 (weight-spill: rounds 6 and 12).
// ---------------------------------------------------------------------------
__global__ __launch_bounds__(512, 2) void lstm2_mfma_kernel(
    const float* __restrict__ inseq,
    const float* __restrict__ in0,
    const _Float16* __restrict__ w1half,
    const float* __restrict__ b1ihp, const float* __restrict__ b1hhp,
    const _Float16* __restrict__ w2half,
    const float* __restrict__ b2ihp, const float* __restrict__ b2hhp,
    const float* __restrict__ h01, const float* __restrict__ c01,
    const float* __restrict__ h02, const float* __restrict__ c02,
    _Float16* __restrict__ outh2,         // fp16 output
    float* __restrict__ hf1, float* __restrict__ cf1,
    float* __restrict__ hf2, float* __restrict__ cf2,
    int S, int mode)
{
    __shared__ __align__(16) _Float16 A1[2][16 * PADH];    // [buf][row][x|h1]
    __shared__ __align__(16) _Float16 A2h[2][16 * PADH2];  // [buf][row][h2]

    const int tid  = threadIdx.x;
    const int w    = tid >> 6;
    const int lrow = tid & 15;
    const int lkg  = (tid >> 4) & 3;
    const int row0 = blockIdx.x * ROWS;

    const bool isL2w = (w >= 4);
    const int  wl    = w & 3;
    const int  hcol  = wl * 16 + lrow;

    const _Float16* wsrc = isL2w ? w2half : w1half;
    const float* bihp = isL2w ? b2ihp : b1ihp;
    const float* bhhp = isL2w ? b2hhp : b1hhp;

    half8 whi[4][4];
    #pragma unroll
    for (int kt = 0; kt < 4; ++kt)
        #pragma unroll
        for (int g = 0; g < 4; ++g) {
            const int col = g * 64 + hcol;
            whi[kt][g] = *(const half8*)&wsrc[(size_t)col * 128 + kt * 32 + lkg * 8];
        }
    float bsv[4];
    #pragma unroll
    for (int g = 0; g < 4; ++g)
        bsv[g] = bihp[g * 64 + hcol] + bhhp[g * 64 + hcol];

    float c[4], hlast[4] = {0.f, 0.f, 0.f, 0.f};

    const float* px[4];       // L1: x(i+1) prefetch stream
    _Float16*    ph[4];       // L2: outh2 store stream

    if (!isL2w) {
        #pragma unroll
        for (int q = 0; q < 4; ++q) {
            const int r = 4 * lkg + q;
            const float* p0 = (mode == 1) ? (in0 + (size_t)(row0 + r) * 64)
                                          : (inseq + (size_t)(row0 + r) * S * 64);
            A1[0][r * PADH + hcol] = (_Float16)p0[hcol];
            float hv = h01 ? h01[(size_t)(row0 + r) * 64 + hcol] : 0.f;
            A1[0][r * PADH + 64 + hcol] = (_Float16)hv;
            c[q] = c01 ? c01[(size_t)(row0 + r) * 64 + hcol] : 0.f;
            px[q] = inseq + (size_t)(row0 + r) * S * 64 + hcol
                  + (mode == 1 ? 0 : 64);
        }
    } else {
        #pragma unroll
        for (int q = 0; q < 4; ++q) {
            const int r = 4 * lkg + q;
            float hv = h02 ? h02[(size_t)(row0 + r) * 64 + hcol] : 0.f;
            A2h[0][r * PADH2 + hcol] = (_Float16)hv;
            c[q] = c02 ? c02[(size_t)(row0 + r) * 64 + hcol] : 0.f;
            ph[q] = outh2 + (size_t)(row0 + r) * S * 64 + hcol;
        }
    }

    const int aoff = lrow * PADH + lkg * 8;

    for (int i = 0; i <= S; ++i) {
        asm volatile("s_waitcnt lgkmcnt(0)" ::: "memory");
        __builtin_amdgcn_s_barrier();
        __builtin_amdgcn_sched_barrier(0);

        if (!isL2w) {
            if (i < S) {
                float xn[4];
                if (i + 1 < S) {
                    #pragma unroll
                    for (int q = 0; q < 4; ++q) { xn[q] = *px[q]; px[q] += 64; }
                }
                const _Float16* As = A1[i & 1];
                f32x4 a0[4];
                #pragma unroll
                for (int g = 0; g < 4; ++g)
                    a0[g] = (f32x4){bsv[g], bsv[g], bsv[g], bsv[g]};
                #pragma unroll
                for (int kt = 0; kt < 4; ++kt) {
                    half8 ah = *(const half8*)&As[aoff + kt * 32];
                    #pragma unroll
                    for (int g = 0; g < 4; ++g)
                        a0[g] = __builtin_amdgcn_mfma_f32_16x16x32_f16(ah, whi[kt][g], a0[g], 0, 0, 0);
                }
                _Float16* Ad1 = A1[(i + 1) & 1];
                #pragma unroll
                for (int q = 0; q < 4; ++q) {
                    const int r = 4 * lkg + q;
                    float gi = a0[0][q], gf = a0[1][q], gg = a0[2][q], go = a0[3][q];
                    c[q] = fsig(gf) * c[q] + fsig(gi) * ftanh(gg);
                    float hv = fsig(go) * ftanh(c[q]);
                    hlast[q] = hv;
                    Ad1[r * PADH + 64 + hcol] = (_Float16)hv;   // h1 -> A1 only
                }
                if (i + 1 < S) {
                    #pragma unroll
                    for (int q = 0; q < 4; ++q) {
                        const int r = 4 * lkg + q;
                        Ad1[r * PADH + hcol] = (_Float16)xn[q];
                    }
                }
            }
        } else {
            const int j = i - 1;
            if (j >= 0 && j < S) {
                const _Float16* Ah1 = A1[(j + 1) & 1];   // h1(j) (h-part)
                const _Float16* Ah2 = A2h[j & 1];        // h2(j-1)
                f32x4 a0[4];
                #pragma unroll
                for (int g = 0; g < 4; ++g)
                    a0[g] = (f32x4){bsv[g], bsv[g], bsv[g], bsv[g]};
                #pragma unroll
                for (int kt = 0; kt < 2; ++kt) {
                    half8 ah = *(const half8*)&Ah1[lrow * PADH + 64 + kt * 32 + lkg * 8];
                    #pragma unroll
                    for (int g = 0; g < 4; ++g)
                        a0[g] = __builtin_amdgcn_mfma_f32_16x16x32_f16(ah, whi[kt][g], a0[g], 0, 0, 0);
                }
                #pragma unroll
                for (int kt = 2; kt < 4; ++kt) {
                    half8 ah = *(const half8*)&Ah2[lrow * PADH2 + (kt - 2) * 32 + lkg * 8];
                    #pragma unroll
                    for (int g = 0; g < 4; ++g)
                        a0[g] = __builtin_amdgcn_mfma_f32_16x16x32_f16(ah, whi[kt][g], a0[g], 0, 0, 0);
                }
                _Float16* Ad = A2h[(j + 1) & 1];
                #pragma unroll
                for (int q = 0; q < 4; ++q) {
                    const int r = 4 * lkg + q;
                    float gi = a0[0][q], gf = a0[1][q], gg = a0[2][q], go = a0[3][q];
                    c[q] = fsig(gf) * c[q] + fsig(gi) * ftanh(gg);
                    float hv = fsig(go) * ftanh(c[q]);
                    hlast[q] = hv;
                    _Float16 hh = (_Float16)hv;
                    Ad[r * PADH2 + hcol] = hh;
                    *ph[q] = hh; ph[q] += 64;
                }
            }
        }
    }
    if (hf1) {
        float* hdst = isL2w ? hf2 : hf1;
        float* cdst = isL2w ? cf2 : cf1;
        #pragma unroll
        for (int q = 0; q < 4; ++q) {
            const int r = 4 * lkg + q;
            hdst[(size_t)(row0 + r) * 64 + hcol] = hlast[q];
            cdst[(size_t)(row0 + r) * 64 + hcol] = c[q];
        }
    }
}

// ---------------------------------------------------------------------------
// Self-attention, last query only — v2 (round-14 known-good).
// ---------------------------------------------------------------------------
__global__ __launch_bounds__(256, 4) void attn0_v2(
    const _Float16* __restrict__ ench,
    const _Float16* __restrict__ wqkvh,   // [192][64] hi plane
    const float* __restrict__ bqkv,
    const float* __restrict__ woT,        // fp32 [k 64][j 64]
    const float* __restrict__ bo,
    float* __restrict__ a0last)
{
    __shared__ __align__(16) _Float16 E[64 * 72];
    __shared__ __align__(16) _Float16 K[64 * 72];
    __shared__ __align__(16) _Float16 V[64 * 72];
    __shared__ __align__(16) _Float16 Q[64 * 72];
    __shared__ float wsm[4 * 68];
    __shared__ float ov[64];
    __shared__ float part[4 * 64];

    const int b = blockIdx.x, tid = threadIdx.x;
    const int w = tid >> 6, l = tid & 63, lr = l & 15, lkg = l >> 4;

    {
        int row = tid >> 2, c0 = (tid & 3) * 16;
        const _Float16* ep = ench + (size_t)b * 4096 + row * 64 + c0;
        *(half8*)&E[row * 72 + c0]     = *(const half8*)ep;
        *(half8*)&E[row * 72 + c0 + 8] = *(const half8*)(ep + 8);
    }
    __syncthreads();

    for (int tt = w; tt < 12; tt += 4) {
        const int kind = tt >> 2;                 // 0=K, 1=V, 2=Q
        const int mrow = (tt & 3) * 16;
        const int wrowB = (kind == 0) ? 64 : ((kind == 1) ? 128 : 0);
        half8 ah[2];
        #pragma unroll
        for (int kt = 0; kt < 2; ++kt)
            ah[kt] = *(const half8*)&E[(mrow + lr) * 72 + kt * 32 + lkg * 8];
        _Float16* dst = (kind == 0) ? K : ((kind == 1) ? V : Q);
        #pragma unroll
        for (int nt = 0; nt < 4; ++nt) {
            const int col = nt * 16 + lr;
            const float bv = bqkv[wrowB + col];
            f32x4 a0 = (f32x4){bv, bv, bv, bv};
            #pragma unroll
            for (int kt = 0; kt < 2; ++kt) {
                half8 bh = *(const half8*)&wqkvh[(size_t)(wrowB + col) * 64 + kt * 32 + lkg * 8];
                a0 = __builtin_amdgcn_mfma_f32_16x16x32_f16(ah[kt], bh, a0, 0, 0, 0);
            }
            #pragma unroll
            for (int i = 0; i < 4; ++i)
                dst[(mrow + lkg * 4 + i) * 72 + col] = (_Float16)a0[i];
        }
    }
    __syncthreads();

    {
        const int kv = l;
        float s = 0.f;
        #pragma unroll
        for (int d = 0; d < 16; ++d)
            s += (float)Q[63 * 72 + w * 16 + d] * (float)K[kv * 72 + w * 16 + d];
        s *= 0.25f;
        float m = s;
        #pragma unroll
        for (int off = 32; off; off >>= 1) m = fmaxf(m, __shfl_xor(m, off));
        float e = __expf(s - m);
        float sum = e;
        #pragma unroll
        for (int off = 32; off; off >>= 1) sum += __shfl_xor(sum, off);
        wsm[w * 68 + kv] = e / sum;
    }
    __syncthreads();

    {
        const int d = l & 15, gr = l >> 4;
        float o = 0.f;
        #pragma unroll
        for (int k = 0; k < 16; ++k) {
            const int kv = gr * 16 + k;
            o += wsm[w * 68 + kv] * (float)V[kv * 72 + w * 16 + d];
        }
        o += __shfl_xor(o, 16);
        o += __shfl_xor(o, 32);
        if (l < 16) ov[w * 16 + l] = o;
    }
    __syncthreads();

    {
        const int j = tid & 63, g = tid >> 6;
        float p = 0.f;
        #pragma unroll
        for (int k = 0; k < 16; ++k) {
            const int kk = g * 16 + k;
            p += ov[kk] * woT[kk * 64 + j];
        }
        part[g * 64 + j] = p;
    }
    __syncthreads();
    if (tid < 64) {
        float a = bo[tid] + part[tid] + part[64 + tid] + part[128 + tid] + part[192 + tid];
        a0last[(size_t)b * 64 + tid] = a;
    }
}

// ---------------------------------------------------------------------------
// Cross-attention v3 (round-11/13/15 known-good): fp16 staging, S^T scores,
// fused out-proj+FC1+FC2 epilogue. 256 threads, 40960 B LDS, 4 blocks/CU.
// ---------------------------------------------------------------------------
__global__ __launch_bounds__(256, 4) void cross_attn_v3(
    const _Float16* __restrict__ ench, const _Float16* __restrict__ dech,
    const _Float16* __restrict__ wqkvh, const float* __restrict__ bqkv,
    const _Float16* __restrict__ woh,   const float* __restrict__ bo,
    const _Float16* __restrict__ w1h,   const float* __restrict__ b1,
    const float* __restrict__ W2,       const float* __restrict__ b2,
    float* __restrict__ pred, float* __restrict__ attnw)
{
    extern __shared__ __align__(16) char smem[];
    _Float16* E  = (_Float16*)(smem);
    _Float16* D  = (_Float16*)(smem + 9216);
    _Float16* K  = (_Float16*)(smem + 16128);
    _Float16* Q  = (_Float16*)(smem + 25344);
    _Float16* VT = (_Float16*)(smem + 32256);
    _Float16* AO = (_Float16*)(smem + 32256);
    float*    Hl = (float*)(smem + 32256);

    const int b = blockIdx.x, tid = threadIdx.x;
    const int w = tid >> 6, l = tid & 63, lr = l & 15, lkg = l >> 4;
    const int h = w;

    {
        int row = tid >> 2, c0 = (tid & 3) * 16;
        const _Float16* ep = ench + (size_t)b * 4096 + row * 64 + c0;
        *(half8*)&E[row * 72 + c0]     = *(const half8*)ep;
        *(half8*)&E[row * 72 + c0 + 8] = *(const half8*)(ep + 8);
        if (row < 48) {
            const _Float16* dp = dech + (size_t)b * 3072 + row * 64 + c0;
            *(half8*)&D[row * 72 + c0]     = *(const half8*)dp;
            *(half8*)&D[row * 72 + c0 + 8] = *(const half8*)(dp + 8);
        }
    }
    __syncthreads();

    for (int tt = w; tt < 11; tt += 4) {
        const int kind = (tt < 4) ? 0 : ((tt < 8) ? 1 : 2);
        const int mrow = ((kind == 0) ? tt : (kind == 1) ? tt - 4 : tt - 8) * 16;
        const int wrowB = (kind == 0) ? 64 : ((kind == 1) ? 128 : 0);
        const _Float16* S = (kind == 2) ? D : E;
        half8 ah[2];
        #pragma unroll
        for (int kt = 0; kt < 2; ++kt)
            ah[kt] = *(const half8*)&S[(mrow + lr) * 72 + kt * 32 + lkg * 8];
        #pragma unroll
        for (int nt = 0; nt < 4; ++nt) {
            const int col = nt * 16 + lr;
            const float bv = bqkv[wrowB + col];
            f32x4 a0 = (f32x4){bv, bv, bv, bv};
            #pragma unroll
            for (int kt = 0; kt < 2; ++kt) {
                half8 bh = *(const half8*)&wqkvh[(size_t)(wrowB + col) * 64 + kt * 32 + lkg * 8];
                a0 = __builtin_amdgcn_mfma_f32_16x16x32_f16(ah[kt], bh, a0, 0, 0, 0);
            }
            if (kind == 1) {
                half4 p;
                #pragma unroll
                for (int i = 0; i < 4; ++i) p[i] = (_Float16)a0[i];
                *(half4*)&VT[col * 68 + mrow + lkg * 4] = p;
            } else {
                _Float16* dst = (kind == 0) ? K : Q;
                #pragma unroll
                for (int i = 0; i < 4; ++i)
                    dst[(mrow + lkg * 4 + i) * 72 + col] = (_Float16)a0[i];
            }
        }
    }
    __syncthreads();

    const half8 z = {0, 0, 0, 0, 0, 0, 0, 0};
    half8 ka[4], qb[3];
    #pragma unroll
    for (int kvt = 0; kvt < 4; ++kvt)
        ka[kvt] = (lkg < 2) ? *(const half8*)&K[(kvt * 16 + lr) * 72 + h * 16 + lkg * 8] : z;
    #pragma unroll
    for (int qt = 0; qt < 3; ++qt)
        qb[qt] = (lkg < 2) ? *(const half8*)&Q[(qt * 16 + lr) * 72 + h * 16 + lkg * 8] : z;
    __syncthreads();

    _Float16* strip = (_Float16*)(smem + ((h == 0) ? 0 : (h == 1) ? 9216
                                        : (h == 2) ? 16128 : 25344));
    {
        f32x4 s[3][4];
        #pragma unroll
        for (int qt = 0; qt < 3; ++qt) {
            #pragma unroll
            for (int kvt = 0; kvt < 4; ++kvt) {
                f32x4 a0 = (f32x4){0.f, 0.f, 0.f, 0.f};
                a0 = __builtin_amdgcn_mfma_f32_16x16x32_f16(ka[kvt], qb[qt], a0, 0, 0, 0);
                s[qt][kvt] = a0 * 0.25f;
            }
            float m = s[qt][0][0];
            #pragma unroll
            for (int kvt = 0; kvt < 4; ++kvt)
                #pragma unroll
                for (int i = 0; i < 4; ++i) m = fmaxf(m, s[qt][kvt][i]);
            m = fmaxf(m, __shfl_xor(m, 16));
            m = fmaxf(m, __shfl_xor(m, 32));
            float sum = 0.f;
            #pragma unroll
            for (int kvt = 0; kvt < 4; ++kvt)
                #pragma unroll
                for (int i = 0; i < 4; ++i) {
                    float e = __expf(s[qt][kvt][i] - m);
                    s[qt][kvt][i] = e;
                    sum += e;
                }
            sum += __shfl_xor(sum, 16);
            sum += __shfl_xor(sum, 32);
            const float r = 1.0f / sum;
            #pragma unroll
            for (int kvt = 0; kvt < 4; ++kvt) {
                half4 p;
                #pragma unroll
                for (int i = 0; i < 4; ++i) p[i] = (_Float16)(s[qt][kvt][i] * r);
                *(half4*)&strip[(qt * 16 + lr) * 72 + kvt * 16 + lkg * 4] = p;
            }
        }
    }
    f32x4 pv[3];
    {
        half8 vb[2];
        #pragma unroll
        for (int kt = 0; kt < 2; ++kt) {
            half4 lo4 = *(const half4*)&VT[(h * 16 + lr) * 68 + kt * 32 + lkg * 8];
            half4 hi4 = *(const half4*)&VT[(h * 16 + lr) * 68 + kt * 32 + lkg * 8 + 4];
            #pragma unroll
            for (int j = 0; j < 4; ++j) { vb[kt][j] = lo4[j]; vb[kt][4 + j] = hi4[j]; }
        }
        #pragma unroll
        for (int qt = 0; qt < 3; ++qt) {
            f32x4 acc = (f32x4){0.f, 0.f, 0.f, 0.f};
            #pragma unroll
            for (int kt = 0; kt < 2; ++kt) {
                half8 wa = *(const half8*)&strip[(qt * 16 + lr) * 72 + kt * 32 + lkg * 8];
                acc = __builtin_amdgcn_mfma_f32_16x16x32_f16(wa, vb[kt], acc, 0, 0, 0);
            }
            pv[qt] = acc;
        }
    }
    __syncthreads();

    #pragma unroll
    for (int qt = 0; qt < 3; ++qt)
        #pragma unroll
        for (int i = 0; i < 4; ++i)
            AO[(qt * 16 + lkg * 4 + i) * 72 + h * 16 + lr] = (_Float16)pv[qt][i];
    __syncthreads();

    if (w < 3) {
        half8 bAO[2];
        #pragma unroll
        for (int kt = 0; kt < 2; ++kt)
            bAO[kt] = *(const half8*)&AO[(w * 16 + lr) * 72 + kt * 32 + lkg * 8];
        f32x4 ov[4];
        #pragma unroll
        for (int nt = 0; nt < 4; ++nt) {
            f32x4 acc = *(const f32x4*)&bo[nt * 16 + lkg * 4];
            #pragma unroll
            for (int kt = 0; kt < 2; ++kt) {
                half8 aW = *(const half8*)&woh[(size_t)(nt * 16 + lr) * 64 + kt * 32 + lkg * 8];
                acc = __builtin_amdgcn_mfma_f32_16x16x32_f16(aW, bAO[kt], acc, 0, 0, 0);
            }
            ov[nt] = acc;
        }
        #pragma unroll
        for (int nt = 0; nt < 4; ++nt) {
            half4 p;
            #pragma unroll
            for (int i = 0; i < 4; ++i) p[i] = (_Float16)ov[nt][i];
            *(half4*)&AO[(w * 16 + lr) * 72 + nt * 16 + lkg * 4] = p;
        }
        half8 bO[2];
        #pragma unroll
        for (int kt = 0; kt < 2; ++kt)
            bO[kt] = *(const half8*)&AO[(w * 16 + lr) * 72 + kt * 32 + lkg * 8];
        #pragma unroll
        for (int nt = 0; nt < 2; ++nt) {
            f32x4 acc = *(const f32x4*)&b1[nt * 16 + lkg * 4];
            #pragma unroll
            for (int kt = 0; kt < 2; ++kt) {
                half8 aW = *(const half8*)&w1h[(size_t)(nt * 16 + lr) * 64 + kt * 32 + lkg * 8];
                acc = __builtin_amdgcn_mfma_f32_16x16x32_f16(aW, bO[kt], acc, 0, 0, 0);
            }
            f32x4 rl;
            #pragma unroll
            for (int i = 0; i < 4; ++i) rl[i] = fmaxf(acc[i], 0.f);
            *(f32x4*)&Hl[(w * 16 + lr) * 36 + nt * 16 + lkg * 4] = rl;
        }
        if (l < 48) {
            const int qr = l / 3, n = l - 3 * qr;
            const int q = w * 16 + qr;
            float a = b2[n];
            #pragma unroll
            for (int m2 = 0; m2 < 32; ++m2) a += Hl[q * 36 + m2] * W2[n * 32 + m2];
            pred[((size_t)b * 48 + q) * 3 + n] = a;
        }
    } else {
        const _Float16* s0 = (const _Float16*)(smem);
        const _Float16* s1 = (const _Float16*)(smem + 9216);
        const _Float16* s2 = (const _Float16*)(smem + 16128);
        const _Float16* s3 = (const _Float16*)(smem + 25344);
        #pragma unroll 4
        for (int it = 0; it < 48; ++it) {
            int idx = l + it * 64;
            int o = (idx >> 6) * 72 + (idx & 63);
            attnw[(size_t)b * 3072 + idx] =
                0.25f * ((float)s0[o] + (float)s1[o] + (float)s2[o] + (float)s3[o]);
        }
    }
}

// ---------------------------------------------------------------------------
extern "C" void kernel_launch(void* const* d_in, const int* in_sizes, int n_in,
                              void* d_out, int out_size, void* d_ws, size_t ws_size,
                              hipStream_t stream) {
    const float* x      = (const float*)d_in[0];
    const float* target = (const float*)d_in[1];
    const float* eWih0 = (const float*)d_in[2],  *eWhh0 = (const float*)d_in[3];
    const float* ebih0 = (const float*)d_in[4],  *ebhh0 = (const float*)d_in[5];
    const float* eWih1 = (const float*)d_in[6],  *eWhh1 = (const float*)d_in[7];
    const float* ebih1 = (const float*)d_in[8],  *ebhh1 = (const float*)d_in[9];
    const float* dWih0 = (const float*)d_in[10], *dWhh0 = (const float*)d_in[11];
    const float* dbih0 = (const float*)d_in[12], *dbhh0 = (const float*)d_in[13];
    const float* dWih1 = (const float*)d_in[14], *dWhh1 = (const float*)d_in[15];
    const float* dbih1 = (const float*)d_in[16], *dbhh1 = (const float*)d_in[17];
    const float* Wqkv = (const float*)d_in[18], *bqkv = (const float*)d_in[19];
    const float* Wo   = (const float*)d_in[20], *bo   = (const float*)d_in[21];
    const float* W1   = (const float*)d_in[22], *b1   = (const float*)d_in[23];
    const float* W2   = (const float*)d_in[24], *b2   = (const float*)d_in[25];

    float* ws = (float*)d_ws;
    float* hseq1  = ws;
    float* encout = hseq1  + (size_t)B_ * L_ * H_;   // layout keeper
    float* decout = encout + (size_t)B_ * L_ * H_;
    float* a0last = decout + (size_t)B_ * T_ * H_;
    float* hfin   = a0last + (size_t)B_ * H_;
    float* cfin   = hfin   + (size_t)2 * B_ * H_;
    float* wtg    = cfin   + (size_t)2 * B_ * H_;
    float* auxw   = wtg    + (size_t)4 * 32768;

    _Float16* wh0 = (_Float16*)(wtg);                // [4][256][128] halves
    _Float16* wh1 = wh0 + 32768;
    _Float16* wh2 = wh1 + 32768;
    _Float16* wh3 = wh2 + 32768;
    _Float16* wqkvh = (_Float16*)auxw;               // 24576 halves
    _Float16* woh   = wqkvh + 24576;                 // 8192
    _Float16* w1h   = woh + 8192;                    // 4096
    float*    woT   = auxw + 18432;                  // 4096 floats
    _Float16* encouth = (_Float16*)hseq1;
    _Float16* decouth = encouth + (size_t)B_ * L_ * H_;

    float* pred  = (float*)d_out;
    float* attnw = pred + (size_t)B_ * T_ * 3;

    transpose_w_all_kernel<<<256, 256, 0, stream>>>(
        eWih0, eWhh0, eWih1, eWhh1, dWih0, dWhh0, dWih1, dWhh1, wh0);
    split_aux_kernel<<<88, 256, 0, stream>>>(Wqkv, Wo, W1, wqkvh, woh, w1h, woT);

    // fused encoder -> fp16 encouth
    lstm2_mfma_kernel<<<B_ / ROWS, 512, 0, stream>>>(
        x, nullptr, wh0, ebih0, ebhh0, wh1, ebih1, ebhh1,
        nullptr, nullptr, nullptr, nullptr,
        encouth, hfin, cfin, hfin + (size_t)B_ * H_, cfin + (size_t)B_ * H_,
        L_, 0);
    // self-attn, last query
    attn0_v2<<<B_, 256, 0, stream>>>(encouth, wqkvh, bqkv, woT, bo, a0last);
    // fused decoder -> fp16 decouth
    lstm2_mfma_kernel<<<B_ / ROWS, 512, 0, stream>>>(
        target, a0last, wh2, dbih0, dbhh0, wh3, dbih1, dbhh1,
        hfin, cfin, hfin + (size_t)B_ * H_, cfin + (size_t)B_ * H_,
        decouth, nullptr, nullptr, nullptr, nullptr, T_, 1);
    // cross-attention + out-proj + FC (fused epilogue) -> pred, attnw
    cross_attn_v3<<<B_, 256, 40960, stream>>>(
        encouth, decouth, wqkvh, bqkv, woh, bo, w1h, b1, W2, b2, pred, attnw);
}